// Round 15
// baseline (479.182 us; speedup 1.0000x reference)
//
#include <hip/hip_runtime.h>
#include <hip/hip_bf16.h>

#define B_ 128
#define N_ 1024
#define E_ 300
#define U_ 128
#define M_ (B_ * N_)   // 131072
#define Z_ (5 * U_)    // 640
#define LMAXT 40       // level buckets (last = overflow, t-ordered)
#define LPAR 14        // levels 1..LPAR-1 parallel GEMMs; rest in tail

typedef __attribute__((ext_vector_type(8))) short bf16x8;
typedef __attribute__((ext_vector_type(4))) float f32x4;
typedef _Float16 f16x4 __attribute__((ext_vector_type(4)));
typedef _Float16 f16x8 __attribute__((ext_vector_type(8)));

__device__ __forceinline__ short f2bf(float f) {
  unsigned u = __builtin_bit_cast(unsigned, f);
  u = (u + 0x7fffu + ((u >> 16) & 1u)) >> 16;
  return (short)u;
}

__device__ __forceinline__ float hsig(float z) {
  float v = __builtin_fmaf(z, 0.2f, 0.5f);
  v = v < 0.f ? 0.f : v;
  v = v > 1.f ? 1.f : v;
  return v;
}

__device__ __forceinline__ float tanh_fast(float x) {
  float p = __expf(2.f * x);
  return 1.f - 2.f * __builtin_amdgcn_rcpf(p + 1.f);
}

__device__ __forceinline__ unsigned pk2(float a, float b) {
  return __builtin_bit_cast(unsigned, __builtin_amdgcn_cvt_pkrtz(a, b));
}

// ---------------- Kernel P: weight prep ------------------------------------
// W16: Wr f16 (640,256); Wk16: kernel f16 (640,128); tkTb: tk^T bf16
// (128 rows x 320 k, zero-padded).
__global__ __launch_bounds__(256) void prep(
    const float* __restrict__ Wr, const float* __restrict__ Wk,
    const float* __restrict__ tk, _Float16* __restrict__ W16,
    _Float16* __restrict__ Wk16, short* __restrict__ tkTb) {
  const int idx = blockIdx.x * 256 + threadIdx.x;
  if (idx < 163840) {
    W16[idx] = (_Float16)Wr[idx];
  } else if (idx < 245760) {
    const int i = idx - 163840;
    Wk16[i] = (_Float16)Wk[i];
  } else if (idx < 286720) {
    const int i = idx - 245760;
    const int n = i / 320, k = i - n * 320;
    tkTb[i] = (k < E_) ? f2bf(tk[k * U_ + n]) : (short)0;
  }
}

// ---------------- Kernel 1: FUSED x = relu(state@tk) -> H,C ; xz -> XZ -----
// Phase A: R8-exact staged bf16 GEMM (proven 105us) with R14 vector
// W-staging. Epilogue: R8-exact scalar H/C stores PLUS f16 LDS transpose.
// Phase B (R10-validated fragments): xz = x @ K^T + bias, B-frags straight
// from L2-resident Wk16, only for blocks whose t-range is active. Phase B
// fills the ~95% idle issue slots of this latency-bound kernel and deletes
// the separate xz_gemm pass (and its ~320MB X re-read).
__global__ __launch_bounds__(256) void x_gemm(
    const float* __restrict__ A, const short* __restrict__ tkTb,
    const _Float16* __restrict__ Wk16, const float* __restrict__ bias,
    const int* __restrict__ nv, float* __restrict__ H, float* __restrict__ C,
    _Float16* __restrict__ XZ) {
  __shared__ __align__(16) short As[64][40];
  __shared__ __align__(16) short Ws[128][40];
  __shared__ __align__(16) _Float16 xls[64][136];
  const int tid = threadIdx.x;
  const int m0 = blockIdx.x * 64;
  const int bb = m0 >> 10, t0 = m0 & (N_ - 1);
  const int nodes = nv[2 * bb], leaves = nv[2 * bb + 1];
  const bool active = (t0 + 64 > leaves) && (t0 < nodes);
  f32x4 acc[8] = {};
  const int lane = tid & 63, wv = tid >> 6;
  const int lr = lane & 15, lg = lane >> 4;

  for (int kc = 0; kc < 10; ++kc) {
    const int k0 = kc * 32;
    {
      const int row = tid >> 2, kk = (tid & 3) * 8;
      const float* src = A + (size_t)(m0 + row) * E_ + k0 + kk;
      bf16x8 v;
      if (k0 + 32 <= E_) {
#pragma unroll
        for (int i = 0; i < 8; ++i) v[i] = f2bf(src[i]);
      } else {
#pragma unroll
        for (int i = 0; i < 8; ++i)
          v[i] = (k0 + kk + i < E_) ? f2bf(src[i]) : (short)0;
      }
      *(bf16x8*)&As[row][kk] = v;
    }
#pragma unroll
    for (int s = 0; s < 2; ++s) {
      const int slot = tid + s * 256;
      const int n = slot & 127, kg = slot >> 7;
      *(bf16x8*)&Ws[n][kg * 8] =
          *(const bf16x8*)(tkTb + (size_t)n * 320 + k0 + kg * 8);
    }
    __syncthreads();
    bf16x8 a = *(const bf16x8*)&As[wv * 16 + lr][lg * 8];
#pragma unroll
    for (int nt = 0; nt < 8; ++nt) {
      bf16x8 b = *(const bf16x8*)&Ws[nt * 16 + lr][lg * 8];
      acc[nt] = __builtin_amdgcn_mfma_f32_16x16x32_bf16(a, b, acc[nt], 0, 0, 0);
    }
    __syncthreads();
  }
  // ---- epilogue: ReLU; R8-exact scalar H/C stores; f16 transpose to xls ---
#pragma unroll
  for (int nt = 0; nt < 8; ++nt) {
#pragma unroll
    for (int r = 0; r < 4; ++r) {
      const int m = m0 + wv * 16 + lg * 4 + r;
      const int n = nt * 16 + lr;
      float v = acc[nt][r];
      v = v > 0.f ? v : 0.f;
      H[(size_t)m * U_ + n] = v;
      C[(size_t)m * U_ + n] = v;
      xls[wv * 16 + lg * 4 + r][nt * 16 + lr] = (_Float16)v;
    }
  }
  if (!active) return;
  __syncthreads();

  // ---- Phase B: xz = x @ K^T + bias ----
  f16x8 pa[4];
#pragma unroll
  for (int kk = 0; kk < 4; ++kk)
    pa[kk] = *(const f16x8*)&xls[wv * 16 + lr][kk * 32 + 8 * lg];
#pragma unroll 4
  for (int nt = 0; nt < 40; ++nt) {
    const int n = nt * 16 + lr;
    const float bv = bias[n];
    f32x4 a2 = {bv, bv, bv, bv};
#pragma unroll
    for (int kk = 0; kk < 4; ++kk) {
      const f16x8 bf =
          *(const f16x8*)(Wk16 + (size_t)n * U_ + kk * 32 + 8 * lg);
      a2 = __builtin_amdgcn_mfma_f32_16x16x32_f16(pa[kk], bf, a2, 0, 0, 0);
    }
#pragma unroll
    for (int r = 0; r < 4; ++r)
      XZ[(size_t)(m0 + wv * 16 + lg * 4 + r) * Z_ + n] = (_Float16)a2[r];
  }
}

// ---------------- Kernel C1: per-batch levelize (parallel fixpoint) --------
__global__ __launch_bounds__(512) void levelize(
    const int* __restrict__ child, const int* __restrict__ nv,
    unsigned char* __restrict__ lv, short* __restrict__ rank,
    int* __restrict__ cnt) {
  const int b = blockIdx.x;
  const int tid = threadIdx.x;
  int nodes = nv[2 * b];
  int leaves = nv[2 * b + 1];
  if (nodes > N_) nodes = N_;
  if (leaves < 0) leaves = 0;

  __shared__ short lvs[N_];
  __shared__ int chs[2 * N_];
  __shared__ int cnts[LMAXT];
  __shared__ int changed;

  for (int i = tid; i < N_; i += 512) lvs[i] = 0;
  for (int i = tid; i < 2 * N_; i += 512) chs[i] = child[(size_t)b * 2 * N_ + i];
  if (tid < LMAXT) cnts[tid] = 0;
  __syncthreads();

  int stable = 0;
  for (int s = 0; s < 64; ++s) {
    if (tid == 0) changed = 0;
    __syncthreads();
    int any = 0;
    for (int t = leaves + tid; t < nodes; t += 512) {
      const int c0 = chs[2 * t], c1 = chs[2 * t + 1];
      const int l0 = (c0 < t && c0 >= 0) ? lvs[c0] : 0;
      const int l1 = (c1 < t && c1 >= 0) ? lvs[c1] : 0;
      const int l = 1 + (l0 > l1 ? l0 : l1);
      if (l > (int)lvs[t]) { lvs[t] = (short)l; any = 1; }
    }
    if (any) changed = 1;
    __syncthreads();
    if (!changed) { stable = 1; break; }
  }
  if (!stable) {
    if (tid == 0) {
      for (int t = leaves; t < nodes; ++t) {
        const int c0 = chs[2 * t], c1 = chs[2 * t + 1];
        const int l0 = (c0 < t && c0 >= 0) ? lvs[c0] : 0;
        const int l1 = (c1 < t && c1 >= 0) ? lvs[c1] : 0;
        lvs[t] = (short)(1 + (l0 > l1 ? l0 : l1));
      }
    }
    __syncthreads();
  }

  for (int t = leaves + tid; t < nodes; t += 512) {
    int l = lvs[t];
    if (l > LMAXT - 1) l = LMAXT - 1;
    lv[b * N_ + t] = (unsigned char)l;
    if (l < LMAXT - 1) rank[b * N_ + t] = (short)atomicAdd(&cnts[l], 1);
  }
  __syncthreads();
  if (tid == 0) {
    for (int t = leaves; t < nodes; ++t)
      if ((int)lvs[t] >= LMAXT - 1) rank[b * N_ + t] = (short)(cnts[LMAXT - 1]++);
  }
  __syncthreads();
  if (tid < LMAXT) cnt[tid * 128 + b] = cnts[tid];
}

// ---------------- Kernel C2: global offsets --------------------------------
__global__ __launch_bounds__(64) void offsets(
    const int* __restrict__ cnt, int* __restrict__ pos, int* __restrict__ goff) {
  const int l = threadIdx.x;
  __shared__ int tot[LMAXT];
  if (l < LMAXT) {
    int s = 0;
    for (int b = 0; b < 128; ++b) {
      pos[l * 128 + b] = s;
      s += cnt[l * 128 + b];
    }
    tot[l] = s;
  }
  __syncthreads();
  if (l == 0) {
    int g = 0;
    for (int i = 0; i < LMAXT; ++i) { goff[i] = g; g += tot[i]; }
    goff[LMAXT] = g;
  }
  __syncthreads();
  if (l < LMAXT) {
    const int g = goff[l];
    for (int b = 0; b < 128; ++b) pos[l * 128 + b] += g;
  }
}

// ---------------- Kernel C3: scatter node list + zero invalid rows ---------
__global__ __launch_bounds__(256) void scatter_zero(
    const int* __restrict__ nv, const unsigned char* __restrict__ lv,
    const short* __restrict__ rank, const int* __restrict__ pos,
    int* __restrict__ glist, float* __restrict__ H) {
  const int b = blockIdx.x;
  const int tid = threadIdx.x;
  int nodes = nv[2 * b];
  int leaves = nv[2 * b + 1];
  if (nodes > N_) nodes = N_;
  if (leaves < 0) leaves = 0;
  for (int t = leaves + tid; t < nodes; t += 256) {
    const int l = lv[b * N_ + t];
    glist[pos[l * 128 + b] + rank[b * N_ + t]] = (b << 10) | t;
  }
  const int total = (N_ - nodes) * U_;
  for (int idx = tid; idx < total; idx += 256)
    H[(size_t)b * N_ * U_ + nodes * U_ + idx] = 0.f;
}

// ---------------- Kernel L: one level as a real MFMA GEMM (R8-exact) -------
__global__ __launch_bounds__(512, 2) void level_gemm(
    int lvl, const _Float16* __restrict__ W16, const int* __restrict__ child,
    const int* __restrict__ goff, const int* __restrict__ glist,
    const _Float16* __restrict__ XZ, float* __restrict__ H,
    float* __restrict__ C) {
  const int base = goff[lvl];
  const int count = goff[lvl + 1] - base;
  if (count <= 0) return;
  const int tid = threadIdx.x;
  const int lane = tid & 63, w = tid >> 6;
  const int col = lane & 15, hi = lane >> 4;
  const int u0 = 16 * w + 4 * hi;
  const int mc = 2 * u0;

  f16x8 afrag[5][8];
  {
    const int rows[5] = {16 * w + col, 128 + 32 * w + 2 * col,
                         129 + 32 * w + 2 * col, 384 + 16 * w + col,
                         512 + 16 * w + col};
#pragma unroll
    for (int rt = 0; rt < 5; ++rt) {
      const _Float16* rs = W16 + (size_t)rows[rt] * 256 + 8 * hi;
#pragma unroll
      for (int kt = 0; kt < 8; ++kt) afrag[rt][kt] = *(const f16x8*)(rs + 32 * kt);
    }
  }

  __shared__ __align__(16) _Float16 hbuf[16][272];

  const int nchunk = (count + 15) >> 4;
  for (int chunk = blockIdx.x; chunk < nchunk; chunk += gridDim.x) {
    const int cb = base + chunk * 16;
    int rem = count - chunk * 16;
    if (rem > 16) rem = 16;

    const int j = tid >> 5, s = tid & 31;
    const int nidj = glist[cb + (j < rem ? j : rem - 1)];
    const int bj = nidj >> 10, tj = nidj & 1023;
    const int chj = child[((size_t)bj << 11) + 2 * tj + (s >> 4)];
    const float* hsrc = H + (((size_t)(bj << 10) + chj) << 7) + ((s & 15) << 3);
    const float4 a0 = *(const float4*)hsrc;
    const float4 a1 = *(const float4*)(hsrc + 4);

    const int nidc = glist[cb + (col < rem ? col : rem - 1)];
    const int bc = nidc >> 10, tc = nidc & 1023;
    const _Float16* xzr = XZ + ((size_t)((bc << 10) | tc)) * Z_;
    const f16x4 xzi = *(const f16x4*)(xzr + u0);
    const f16x8 xzf = *(const f16x8*)(xzr + 128 + mc);
    const f16x4 xzo = *(const f16x4*)(xzr + 384 + u0);
    const f16x4 xzg = *(const f16x4*)(xzr + 512 + u0);
    const int csel = child[((size_t)bc << 11) + 2 * tc + (mc >> 7)];
    const float* cbp = C + (((size_t)(bc << 10) + csel) << 7) + (mc & 127);
    const float4 cv0 = ((const float4*)cbp)[0];
    const float4 cv1 = ((const float4*)cbp)[1];

    uint4 hp;
    hp.x = pk2(a0.x, a0.y);
    hp.y = pk2(a0.z, a0.w);
    hp.z = pk2(a1.x, a1.y);
    hp.w = pk2(a1.z, a1.w);
    *(uint4*)&hbuf[j][(s >> 4) * 128 + (s & 15) * 8] = hp;
    __syncthreads();

    f32x4 acc[5];
#pragma unroll
    for (int r = 0; r < 4; ++r) {
      acc[0][r] = (float)xzi[r];
      acc[1][r] = (float)xzf[2 * r];
      acc[2][r] = (float)xzf[2 * r + 1];
      acc[3][r] = (float)xzo[r];
      acc[4][r] = (float)xzg[r];
    }
#pragma unroll
    for (int kt = 0; kt < 8; ++kt) {
      const f16x8 bf = *(const f16x8*)&hbuf[col][32 * kt + 8 * hi];
#pragma unroll
      for (int rt = 0; rt < 5; ++rt)
        acc[rt] = __builtin_amdgcn_mfma_f32_16x16x32_f16(afrag[rt][kt], bf,
                                                         acc[rt], 0, 0, 0);
    }

    const float ce[8] = {cv0.x, cv0.y, cv0.z, cv0.w,
                         cv1.x, cv1.y, cv1.z, cv1.w};
    f32x4 hn4, cn4;
#pragma unroll
    for (int r = 0; r < 4; ++r) {
      const float cn = ce[2 * r] * hsig(acc[1][r]) +
                       ce[2 * r + 1] * hsig(acc[2][r]) +
                       hsig(acc[0][r]) * tanh_fast(acc[4][r]);
      cn4[r] = cn;
      hn4[r] = hsig(acc[3][r]) * tanh_fast(cn);
    }
    if (col < rem) {
      const size_t rowb = ((size_t)((bc << 10) | tc)) << 7;
      *(f32x4*)(H + rowb + u0) = hn4;
      *(f32x4*)(C + rowb + u0) = cn4;
    }
    __syncthreads();
  }
}

// ---------------- Kernel T: sequential tail for levels >= LPAR -------------
__global__ __launch_bounds__(512, 2) void tail_scan(
    const _Float16* __restrict__ W16, const int* __restrict__ child,
    const int* __restrict__ nv, const int* __restrict__ pos,
    const int* __restrict__ cnt, const int* __restrict__ glist,
    const _Float16* __restrict__ XZ, float* __restrict__ H,
    float* __restrict__ C) {
  const int b = blockIdx.x;
  const int tid = threadIdx.x;
  const int lane = tid & 63, w = tid >> 6;
  const int col = lane & 15, hi = lane >> 4;
  const int u0 = 16 * w + 4 * hi;
  const int mc = 2 * u0;
  const int m4 = 4 * lane;

  f16x8 afrag[5][8];
  {
    const int rows[5] = {16 * w + col, 128 + 32 * w + 2 * col,
                         129 + 32 * w + 2 * col, 384 + 16 * w + col,
                         512 + 16 * w + col};
#pragma unroll
    for (int rt = 0; rt < 5; ++rt) {
      const _Float16* rs = W16 + (size_t)rows[rt] * 256 + 8 * hi;
#pragma unroll
      for (int kt = 0; kt < 8; ++kt) afrag[rt][kt] = *(const f16x8*)(rs + 32 * kt);
    }
  }

  __shared__ __align__(16) _Float16 hb1[256];
  const int* chb = child + (size_t)b * 2 * N_;
  float* Hb = H + (size_t)b * N_ * U_;
  float* Cb = C + (size_t)b * N_ * U_;
  const _Float16* xzb = XZ + (size_t)b * N_ * Z_;

  for (int l = LPAR; l < LMAXT; ++l) {
    const int p0 = pos[l * 128 + b];
    const int n = cnt[l * 128 + b];
    for (int i = 0; i < n; ++i) {
      const int t = glist[p0 + i] & 1023;
      if (tid < 64) {
        const int ch = chb[2 * t + (m4 >> 7)];
        const float4 hv = *(const float4*)(Hb + ((size_t)ch << 7) + (m4 & 127));
        uint2 hp;
        hp.x = pk2(hv.x, hv.y);
        hp.y = pk2(hv.z, hv.w);
        *(uint2*)&hb1[m4] = hp;
      }
      const int cs = chb[2 * t + (mc >> 7)];
      const float* cbp = Cb + ((size_t)cs << 7) + (mc & 127);
      const float4 cv0 = ((const float4*)cbp)[0];
      const float4 cv1 = ((const float4*)cbp)[1];
      const _Float16* xzr = xzb + (size_t)t * Z_;
      const f16x4 xzi = *(const f16x4*)(xzr + u0);
      const f16x8 xzf = *(const f16x8*)(xzr + 128 + mc);
      const f16x4 xzo = *(const f16x4*)(xzr + 384 + u0);
      const f16x4 xzg = *(const f16x4*)(xzr + 512 + u0);
      __syncthreads();
      f32x4 acc[5];
#pragma unroll
      for (int r = 0; r < 4; ++r) {
        acc[0][r] = (float)xzi[r];
        acc[1][r] = (float)xzf[2 * r];
        acc[2][r] = (float)xzf[2 * r + 1];
        acc[3][r] = (float)xzo[r];
        acc[4][r] = (float)xzg[r];
      }
#pragma unroll
      for (int kt = 0; kt < 8; ++kt) {
        const f16x8 bf = *(const f16x8*)&hb1[32 * kt + 8 * hi];
#pragma unroll
        for (int rt = 0; rt < 5; ++rt)
          acc[rt] = __builtin_amdgcn_mfma_f32_16x16x32_f16(afrag[rt][kt], bf,
                                                           acc[rt], 0, 0, 0);
      }
      const float ce[8] = {cv0.x, cv0.y, cv0.z, cv0.w,
                           cv1.x, cv1.y, cv1.z, cv1.w};
      f32x4 hn4, cn4;
#pragma unroll
      for (int r = 0; r < 4; ++r) {
        const float cn = ce[2 * r] * hsig(acc[1][r]) +
                         ce[2 * r + 1] * hsig(acc[2][r]) +
                         hsig(acc[0][r]) * tanh_fast(acc[4][r]);
        cn4[r] = cn;
        hn4[r] = hsig(acc[3][r]) * tanh_fast(cn);
      }
      if (col == 0) {
        *(f32x4*)(Hb + ((size_t)t << 7) + u0) = hn4;
        *(f32x4*)(Cb + ((size_t)t << 7) + u0) = cn4;
      }
      __syncthreads();
    }
  }
}

extern "C" void kernel_launch(void* const* d_in, const int* in_sizes, int n_in,
                              void* d_out, int out_size, void* d_ws,
                              size_t ws_size, hipStream_t stream) {
  const float* state = (const float*)d_in[0];
  const float* tk    = (const float*)d_in[1];
  const float* Wk    = (const float*)d_in[2];
  const float* Wr    = (const float*)d_in[3];
  const float* bias  = (const float*)d_in[4];
  const int*   child = (const int*)d_in[5];
  const int*   nvp   = (const int*)d_in[6];
  float* H = (float*)d_out;

  // meta (2 MiB): W16 | Wk16 | tkTb | lv | rank | cnt | pos | goff | glist
  char* wsb = (char*)d_ws;
  _Float16* W16   = (_Float16*)(wsb + 0x000000);  // 320K
  _Float16* Wk16  = (_Float16*)(wsb + 0x050000);  // 160K
  short* tkTb     = (short*)(wsb + 0x078000);     // 80K
  unsigned char* lv = (unsigned char*)(wsb + 0x08C000);  // 128K
  short* rank     = (short*)(wsb + 0x0AC000);            // 256K
  int* cnt        = (int*)(wsb + 0x0EC000);
  int* pos        = (int*)(wsb + 0x0F1000);
  int* goff       = (int*)(wsb + 0x0F6000);
  int* glist      = (int*)(wsb + 0x0F7000);              // 512K
  const size_t meta_sz = 2ull * 1024 * 1024;
  const size_t c_bytes = (size_t)M_ * U_ * sizeof(float);  // 64 MiB
  float* C = (float*)(wsb + meta_sz);
  _Float16* XZ = (_Float16*)(wsb + meta_sz + c_bytes);     // 160 MiB

  prep<<<1120, 256, 0, stream>>>(Wr, Wk, tk, W16, Wk16, tkTb);
  x_gemm<<<M_ / 64, 256, 0, stream>>>(state, tkTb, Wk16, bias, nvp, H, C, XZ);
  levelize<<<B_, 512, 0, stream>>>(child, nvp, lv, rank, cnt);
  offsets<<<1, 64, 0, stream>>>(cnt, pos, goff);
  scatter_zero<<<B_, 256, 0, stream>>>(nvp, lv, rank, pos, glist, H);
  static const int lg[LPAR] = {0, 512, 512, 256, 256, 128, 128,
                               64, 64, 64, 32, 32, 32, 32};
  for (int l = 1; l < LPAR; ++l)
    level_gemm<<<lg[l], 512, 0, stream>>>(l, W16, child, goff, glist, XZ, H,
                                          C);
  tail_scan<<<B_, 512, 0, stream>>>(W16, child, nvp, pos, cnt, glist, XZ, H,
                                    C);
}

// Round 16
// 426.566 us; speedup vs baseline: 1.1233x; 1.1233x over previous
//
#include <hip/hip_runtime.h>
#include <hip/hip_bf16.h>

#define B_ 128
#define N_ 1024
#define E_ 300
#define U_ 128
#define M_ (B_ * N_)   // 131072
#define Z_ (5 * U_)    // 640
#define LMAXT 40       // level buckets (last = overflow, t-ordered)
#define LPAR 14        // levels 1..LPAR-1 parallel GEMMs; rest in tail

typedef __attribute__((ext_vector_type(8))) short bf16x8;
typedef __attribute__((ext_vector_type(4))) float f32x4;
typedef _Float16 f16x4 __attribute__((ext_vector_type(4)));
typedef _Float16 f16x8 __attribute__((ext_vector_type(8)));

__device__ __forceinline__ short f2bf(float f) {
  unsigned u = __builtin_bit_cast(unsigned, f);
  u = (u + 0x7fffu + ((u >> 16) & 1u)) >> 16;
  return (short)u;
}

__device__ __forceinline__ float hsig(float z) {
  float v = __builtin_fmaf(z, 0.2f, 0.5f);
  v = v < 0.f ? 0.f : v;
  v = v > 1.f ? 1.f : v;
  return v;
}

__device__ __forceinline__ float tanh_fast(float x) {
  float p = __expf(2.f * x);
  return 1.f - 2.f * __builtin_amdgcn_rcpf(p + 1.f);
}

__device__ __forceinline__ unsigned pk2(float a, float b) {
  return __builtin_bit_cast(unsigned, __builtin_amdgcn_cvt_pkrtz(a, b));
}

__device__ __forceinline__ f16x8 pack8(float4 a, float4 b) {
  uint4 u;
  u.x = pk2(a.x, a.y);
  u.y = pk2(a.z, a.w);
  u.z = pk2(b.x, b.y);
  u.w = pk2(b.z, b.w);
  return __builtin_bit_cast(f16x8, u);
}

// ---------------- Kernel P: weight prep ------------------------------------
__global__ __launch_bounds__(256) void prep(
    const float* __restrict__ Wr, const float* __restrict__ Wk,
    const float* __restrict__ tk, _Float16* __restrict__ W16,
    _Float16* __restrict__ Wk16, short* __restrict__ tkTb) {
  const int idx = blockIdx.x * 256 + threadIdx.x;
  if (idx < 163840) {
    W16[idx] = (_Float16)Wr[idx];
  } else if (idx < 245760) {
    const int i = idx - 163840;
    Wk16[i] = (_Float16)Wk[i];
  } else if (idx < 286720) {
    const int i = idx - 245760;
    const int n = i / 320, k = i - n * 320;
    tkTb[i] = (k < E_) ? f2bf(tk[k * U_ + n]) : (short)0;
  }
}

// ---------------- Kernel 1: x = relu(state @ Tk) -> H, C (masked) ----------
// R8-exact staged pipeline + tkTb vector W-staging. Valid-mask folded in:
// rows t >= nodes store 0 (replaces scatter_zero's zeroing pass).
__global__ __launch_bounds__(256) void x_gemm(
    const float* __restrict__ A, const short* __restrict__ tkTb,
    const int* __restrict__ nv, float* __restrict__ H, float* __restrict__ C) {
  __shared__ __align__(16) short As[64][40];
  __shared__ __align__(16) short Ws[128][40];
  const int tid = threadIdx.x;
  const int m0 = blockIdx.x * 64;
  const int nodes = nv[2 * (m0 >> 10)];
  const int t0 = m0 & (N_ - 1);
  f32x4 acc[8] = {};
  const int lane = tid & 63, wv = tid >> 6;
  const int lr = lane & 15, lg = lane >> 4;

  for (int kc = 0; kc < 10; ++kc) {
    const int k0 = kc * 32;
    {
      const int row = tid >> 2, kk = (tid & 3) * 8;
      const float* src = A + (size_t)(m0 + row) * E_ + k0 + kk;
      bf16x8 v;
      if (k0 + 32 <= E_) {
#pragma unroll
        for (int i = 0; i < 8; ++i) v[i] = f2bf(src[i]);
      } else {
#pragma unroll
        for (int i = 0; i < 8; ++i)
          v[i] = (k0 + kk + i < E_) ? f2bf(src[i]) : (short)0;
      }
      *(bf16x8*)&As[row][kk] = v;
    }
#pragma unroll
    for (int s = 0; s < 2; ++s) {
      const int slot = tid + s * 256;
      const int n = slot & 127, kg = slot >> 7;
      *(bf16x8*)&Ws[n][kg * 8] =
          *(const bf16x8*)(tkTb + (size_t)n * 320 + k0 + kg * 8);
    }
    __syncthreads();
    bf16x8 a = *(const bf16x8*)&As[wv * 16 + lr][lg * 8];
#pragma unroll
    for (int nt = 0; nt < 8; ++nt) {
      bf16x8 b = *(const bf16x8*)&Ws[nt * 16 + lr][lg * 8];
      acc[nt] = __builtin_amdgcn_mfma_f32_16x16x32_bf16(a, b, acc[nt], 0, 0, 0);
    }
    __syncthreads();
  }
#pragma unroll
  for (int nt = 0; nt < 8; ++nt) {
#pragma unroll
    for (int r = 0; r < 4; ++r) {
      const int m = m0 + wv * 16 + lg * 4 + r;
      const int trow = t0 + wv * 16 + lg * 4 + r;
      const int n = nt * 16 + lr;
      float v = acc[nt][r];
      v = v > 0.f ? v : 0.f;
      if (trow >= nodes) v = 0.f;   // valid-mask folded in
      H[(size_t)m * U_ + n] = v;
      C[(size_t)m * U_ + n] = v;
    }
  }
}

// ---------------- Kernel 2: xz = x @ K^T + bias (f16 staged + stores) ------
__global__ __launch_bounds__(256) void xz_gemm(
    const float* __restrict__ X, const _Float16* __restrict__ Wk16,
    const float* __restrict__ bias, const int* __restrict__ nv,
    _Float16* __restrict__ XZ) {
  const int m0 = blockIdx.x * 64;
  {
    const int bb = m0 >> 10;
    const int t0 = m0 & (N_ - 1);
    const int nodes = nv[2 * bb], leaves = nv[2 * bb + 1];
    if (t0 + 64 <= leaves || t0 >= nodes) return;
  }
  __shared__ __align__(16) short As[64][40];
  __shared__ __align__(16) short Ws[128][40];
  __shared__ __align__(16) _Float16 xzls[64][136];
  const int tid = threadIdx.x;
  const int n0 = blockIdx.y * 128;
  f32x4 acc[8] = {};
  const int lane = tid & 63, wv = tid >> 6;
  const int lr = lane & 15, lg = lane >> 4;

  for (int kc = 0; kc < 4; ++kc) {
    const int k0 = kc * 32;
    {
      const int row = tid >> 2, kk = (tid & 3) * 8;
      const float* src = X + (size_t)(m0 + row) * U_ + k0 + kk;
      const float4 a0 = *(const float4*)src;
      const float4 a1 = *(const float4*)(src + 4);
      *(f16x8*)&As[row][kk] = pack8(a0, a1);
    }
#pragma unroll
    for (int s = 0; s < 2; ++s) {
      const int slot = tid + s * 256;
      const int n = slot >> 2, kk = (slot & 3) * 8;
      *(f16x8*)&Ws[n][kk] =
          *(const f16x8*)(Wk16 + (size_t)(n0 + n) * U_ + k0 + kk);
    }
    __syncthreads();
    f16x8 a = *(const f16x8*)&As[wv * 16 + lr][lg * 8];
#pragma unroll
    for (int nt = 0; nt < 8; ++nt) {
      f16x8 b = *(const f16x8*)&Ws[nt * 16 + lr][lg * 8];
      acc[nt] = __builtin_amdgcn_mfma_f32_16x16x32_f16(a, b, acc[nt], 0, 0, 0);
    }
    __syncthreads();
  }
#pragma unroll
  for (int nt = 0; nt < 8; ++nt) {
    const float bv = bias[n0 + nt * 16 + lr];
#pragma unroll
    for (int r = 0; r < 4; ++r)
      xzls[wv * 16 + lg * 4 + r][nt * 16 + lr] = (_Float16)(acc[nt][r] + bv);
  }
  __syncthreads();
  {
    const int row = tid >> 2, c0 = (tid & 3) * 32;
    _Float16* dst = XZ + (size_t)(m0 + row) * Z_ + n0 + c0;
#pragma unroll
    for (int s = 0; s < 4; ++s)
      *(f16x8*)(dst + 8 * s) = *(const f16x8*)&xzls[row][c0 + 8 * s];
  }
}

// ---------------- Kernel C1: per-batch levelize (parallel fixpoint) --------
__global__ __launch_bounds__(512) void levelize(
    const int* __restrict__ child, const int* __restrict__ nv,
    unsigned char* __restrict__ lv, short* __restrict__ rank,
    int* __restrict__ cnt) {
  const int b = blockIdx.x;
  const int tid = threadIdx.x;
  int nodes = nv[2 * b];
  int leaves = nv[2 * b + 1];
  if (nodes > N_) nodes = N_;
  if (leaves < 0) leaves = 0;

  __shared__ short lvs[N_];
  __shared__ int chs[2 * N_];
  __shared__ int cnts[LMAXT];
  __shared__ int changed;

  for (int i = tid; i < N_; i += 512) lvs[i] = 0;
  for (int i = tid; i < 2 * N_; i += 512) chs[i] = child[(size_t)b * 2 * N_ + i];
  if (tid < LMAXT) cnts[tid] = 0;
  __syncthreads();

  int stable = 0;
  for (int s = 0; s < 64; ++s) {
    if (tid == 0) changed = 0;
    __syncthreads();
    int any = 0;
    for (int t = leaves + tid; t < nodes; t += 512) {
      const int c0 = chs[2 * t], c1 = chs[2 * t + 1];
      const int l0 = (c0 < t && c0 >= 0) ? lvs[c0] : 0;
      const int l1 = (c1 < t && c1 >= 0) ? lvs[c1] : 0;
      const int l = 1 + (l0 > l1 ? l0 : l1);
      if (l > (int)lvs[t]) { lvs[t] = (short)l; any = 1; }
    }
    if (any) changed = 1;
    __syncthreads();
    if (!changed) { stable = 1; break; }
  }
  if (!stable) {
    if (tid == 0) {
      for (int t = leaves; t < nodes; ++t) {
        const int c0 = chs[2 * t], c1 = chs[2 * t + 1];
        const int l0 = (c0 < t && c0 >= 0) ? lvs[c0] : 0;
        const int l1 = (c1 < t && c1 >= 0) ? lvs[c1] : 0;
        lvs[t] = (short)(1 + (l0 > l1 ? l0 : l1));
      }
    }
    __syncthreads();
  }

  for (int t = leaves + tid; t < nodes; t += 512) {
    int l = lvs[t];
    if (l > LMAXT - 1) l = LMAXT - 1;
    lv[b * N_ + t] = (unsigned char)l;
    if (l < LMAXT - 1) rank[b * N_ + t] = (short)atomicAdd(&cnts[l], 1);
  }
  __syncthreads();
  if (tid == 0) {
    for (int t = leaves; t < nodes; ++t)
      if ((int)lvs[t] >= LMAXT - 1) rank[b * N_ + t] = (short)(cnts[LMAXT - 1]++);
  }
  __syncthreads();
  if (tid < LMAXT) cnt[tid * 128 + b] = cnts[tid];
}

// ---------------- Kernel C2: global offsets --------------------------------
__global__ __launch_bounds__(64) void offsets(
    const int* __restrict__ cnt, int* __restrict__ pos, int* __restrict__ goff) {
  const int l = threadIdx.x;
  __shared__ int tot[LMAXT];
  if (l < LMAXT) {
    int s = 0;
    for (int b = 0; b < 128; ++b) {
      pos[l * 128 + b] = s;
      s += cnt[l * 128 + b];
    }
    tot[l] = s;
  }
  __syncthreads();
  if (l == 0) {
    int g = 0;
    for (int i = 0; i < LMAXT; ++i) { goff[i] = g; g += tot[i]; }
    goff[LMAXT] = g;
  }
  __syncthreads();
  if (l < LMAXT) {
    const int g = goff[l];
    for (int b = 0; b < 128; ++b) pos[l * 128 + b] += g;
  }
}

// ---------------- Kernel C3: scatter node list (zeroing now in x_gemm) -----
__global__ __launch_bounds__(256) void scatter(
    const int* __restrict__ nv, const unsigned char* __restrict__ lv,
    const short* __restrict__ rank, const int* __restrict__ pos,
    int* __restrict__ glist) {
  const int b = blockIdx.x;
  const int tid = threadIdx.x;
  int nodes = nv[2 * b];
  int leaves = nv[2 * b + 1];
  if (nodes > N_) nodes = N_;
  if (leaves < 0) leaves = 0;
  for (int t = leaves + tid; t < nodes; t += 256) {
    const int l = lv[b * N_ + t];
    glist[pos[l * 128 + b] + rank[b * N_ + t]] = (b << 10) | t;
  }
}

// ---------------- chunk-load helper for level_gemm (f32 gathers) -----------
struct ChunkLd {
  float4 a0, a1;    // h_ch slice (per-lane j,s)
  float4 cv0, cv1;  // c_ch slice (per-lane col)
  f16x4 xzi, xzo, xzg;
  f16x8 xzf;
  int nid, rem;
};

__device__ __forceinline__ ChunkLd load_chunk(
    int chunk, int nchunk, int base, int count, const int* __restrict__ glist,
    const int* __restrict__ child, const _Float16* __restrict__ XZ,
    const float* __restrict__ H, const float* __restrict__ C, int j, int s,
    int col, int u0, int mc) {
  ChunkLd r;
  const int cc = chunk < nchunk - 1 ? chunk : nchunk - 1;
  const int cb = base + cc * 16;
  int rem = count - cc * 16;
  if (rem > 16) rem = 16;
  r.rem = rem;

  const int nidj = glist[cb + (j < rem ? j : rem - 1)];
  const int bj = nidj >> 10, tj = nidj & 1023;
  const int chj = child[((size_t)bj << 11) + 2 * tj + (s >> 4)];
  const float* hsrc = H + (((size_t)(bj << 10) + chj) << 7) + ((s & 15) << 3);
  r.a0 = *(const float4*)hsrc;
  r.a1 = *(const float4*)(hsrc + 4);

  const int nidc = glist[cb + (col < rem ? col : rem - 1)];
  r.nid = nidc;
  const _Float16* xzr = XZ + (size_t)nidc * Z_;
  r.xzi = *(const f16x4*)(xzr + u0);
  r.xzf = *(const f16x8*)(xzr + 128 + mc);
  r.xzo = *(const f16x4*)(xzr + 384 + u0);
  r.xzg = *(const f16x4*)(xzr + 512 + u0);
  const int bc = nidc >> 10, tc = nidc & 1023;
  const int csel = child[((size_t)bc << 11) + 2 * tc + (mc >> 7)];
  const float* cbp = C + (((size_t)(bc << 10) + csel) << 7) + (mc & 127);
  r.cv0 = ((const float4*)cbp)[0];
  r.cv1 = ((const float4*)cbp)[1];
  return r;
}

// ---------------- Kernel L: one level, pipelined chunks, no vmcnt drain ----
__global__ __launch_bounds__(512, 2) void level_gemm(
    int lvl, const _Float16* __restrict__ W16, const int* __restrict__ child,
    const int* __restrict__ goff, const int* __restrict__ glist,
    const _Float16* __restrict__ XZ, float* __restrict__ H,
    float* __restrict__ C) {
  const int base = goff[lvl];
  const int count = goff[lvl + 1] - base;
  if (count <= 0) return;
  const int nchunk = (count + 15) >> 4;
  if ((int)blockIdx.x >= nchunk) return;
  const int tid = threadIdx.x;
  const int lane = tid & 63, w = tid >> 6;
  const int col = lane & 15, hi = lane >> 4;
  const int u0 = 16 * w + 4 * hi;
  const int mc = 2 * u0;
  const int j = tid >> 5, s = tid & 31;

  f16x8 afrag[5][8];
  {
    const int rows[5] = {16 * w + col, 128 + 32 * w + 2 * col,
                         129 + 32 * w + 2 * col, 384 + 16 * w + col,
                         512 + 16 * w + col};
#pragma unroll
    for (int rt = 0; rt < 5; ++rt) {
      const _Float16* rs = W16 + (size_t)rows[rt] * 256 + 8 * hi;
#pragma unroll
      for (int kt = 0; kt < 8; ++kt) afrag[rt][kt] = *(const f16x8*)(rs + 32 * kt);
    }
  }

  __shared__ __align__(16) _Float16 hbuf[2][16][272];

  ChunkLd cur = load_chunk(blockIdx.x, nchunk, base, count, glist, child, XZ,
                           H, C, j, s, col, u0, mc);
  int p = 0;
  for (int chunk = blockIdx.x; chunk < nchunk; chunk += gridDim.x) {
    uint4 hp;
    hp.x = pk2(cur.a0.x, cur.a0.y);
    hp.y = pk2(cur.a0.z, cur.a0.w);
    hp.z = pk2(cur.a1.x, cur.a1.y);
    hp.w = pk2(cur.a1.z, cur.a1.w);
    *(uint4*)&hbuf[p][j][(s >> 4) * 128 + (s & 15) * 8] = hp;

    ChunkLd nxt = load_chunk(chunk + gridDim.x < nchunk ? chunk + gridDim.x
                                                        : nchunk - 1,
                             nchunk, base, count, glist, child, XZ, H, C, j, s,
                             col, u0, mc);

    asm volatile("s_waitcnt lgkmcnt(0)" ::: "memory");
    __builtin_amdgcn_sched_barrier(0);
    __builtin_amdgcn_s_barrier();
    __builtin_amdgcn_sched_barrier(0);

    f32x4 acc[5];
#pragma unroll
    for (int r = 0; r < 4; ++r) {
      acc[0][r] = (float)cur.xzi[r];
      acc[1][r] = (float)cur.xzf[2 * r];
      acc[2][r] = (float)cur.xzf[2 * r + 1];
      acc[3][r] = (float)cur.xzo[r];
      acc[4][r] = (float)cur.xzg[r];
    }
#pragma unroll
    for (int kt = 0; kt < 8; ++kt) {
      const f16x8 bf = *(const f16x8*)&hbuf[p][col][32 * kt + 8 * hi];
#pragma unroll
      for (int rt = 0; rt < 5; ++rt)
        acc[rt] = __builtin_amdgcn_mfma_f32_16x16x32_f16(afrag[rt][kt], bf,
                                                         acc[rt], 0, 0, 0);
    }

    const float ce[8] = {cur.cv0.x, cur.cv0.y, cur.cv0.z, cur.cv0.w,
                         cur.cv1.x, cur.cv1.y, cur.cv1.z, cur.cv1.w};
    f32x4 hn4, cn4;
#pragma unroll
    for (int r = 0; r < 4; ++r) {
      const float cn = ce[2 * r] * hsig(acc[1][r]) +
                       ce[2 * r + 1] * hsig(acc[2][r]) +
                       hsig(acc[0][r]) * tanh_fast(acc[4][r]);
      cn4[r] = cn;
      hn4[r] = hsig(acc[3][r]) * tanh_fast(cn);
    }
    if (col < cur.rem) {
      const size_t rowb = (size_t)cur.nid << 7;
      *(f32x4*)(H + rowb + u0) = hn4;
      *(f32x4*)(C + rowb + u0) = cn4;
    }
    cur = nxt;
    p ^= 1;
  }
}

// ---------------- Kernel T: sequential tail for levels >= LPAR -------------
__global__ __launch_bounds__(512, 2) void tail_scan(
    const _Float16* __restrict__ W16, const int* __restrict__ child,
    const int* __restrict__ nv, const int* __restrict__ pos,
    const int* __restrict__ cnt, const int* __restrict__ glist,
    const _Float16* __restrict__ XZ, float* __restrict__ H,
    float* __restrict__ C) {
  const int b = blockIdx.x;
  const int tid = threadIdx.x;
  const int lane = tid & 63, w = tid >> 6;
  const int col = lane & 15, hi = lane >> 4;
  const int u0 = 16 * w + 4 * hi;
  const int mc = 2 * u0;
  const int m4 = 4 * lane;

  f16x8 afrag[5][8];
  {
    const int rows[5] = {16 * w + col, 128 + 32 * w + 2 * col,
                         129 + 32 * w + 2 * col, 384 + 16 * w + col,
                         512 + 16 * w + col};
#pragma unroll
    for (int rt = 0; rt < 5; ++rt) {
      const _Float16* rs = W16 + (size_t)rows[rt] * 256 + 8 * hi;
#pragma unroll
      for (int kt = 0; kt < 8; ++kt) afrag[rt][kt] = *(const f16x8*)(rs + 32 * kt);
    }
  }

  __shared__ __align__(16) _Float16 hb1[256];
  const int* chb = child + (size_t)b * 2 * N_;
  float* Hb = H + (size_t)b * N_ * U_;
  float* Cb = C + (size_t)b * N_ * U_;
  const _Float16* xzb = XZ + (size_t)b * N_ * Z_;

  for (int l = LPAR; l < LMAXT; ++l) {
    const int p0 = pos[l * 128 + b];
    const int n = cnt[l * 128 + b];
    for (int i = 0; i < n; ++i) {
      const int t = glist[p0 + i] & 1023;
      if (tid < 64) {
        const int ch = chb[2 * t + (m4 >> 7)];
        const float4 hv = *(const float4*)(Hb + ((size_t)ch << 7) + (m4 & 127));
        uint2 hp;
        hp.x = pk2(hv.x, hv.y);
        hp.y = pk2(hv.z, hv.w);
        *(uint2*)&hb1[m4] = hp;
      }
      const int cs = chb[2 * t + (mc >> 7)];
      const float* cbp = Cb + ((size_t)cs << 7) + (mc & 127);
      const float4 cv0 = ((const float4*)cbp)[0];
      const float4 cv1 = ((const float4*)cbp)[1];
      const _Float16* xzr = xzb + (size_t)t * Z_;
      const f16x4 xzi = *(const f16x4*)(xzr + u0);
      const f16x8 xzf = *(const f16x8*)(xzr + 128 + mc);
      const f16x4 xzo = *(const f16x4*)(xzr + 384 + u0);
      const f16x4 xzg = *(const f16x4*)(xzr + 512 + u0);
      __syncthreads();
      f32x4 acc[5];
#pragma unroll
      for (int r = 0; r < 4; ++r) {
        acc[0][r] = (float)xzi[r];
        acc[1][r] = (float)xzf[2 * r];
        acc[2][r] = (float)xzf[2 * r + 1];
        acc[3][r] = (float)xzo[r];
        acc[4][r] = (float)xzg[r];
      }
#pragma unroll
      for (int kt = 0; kt < 8; ++kt) {
        const f16x8 bf = *(const f16x8*)&hb1[32 * kt + 8 * hi];
#pragma unroll
        for (int rt = 0; rt < 5; ++rt)
          acc[rt] = __builtin_amdgcn_mfma_f32_16x16x32_f16(afrag[rt][kt], bf,
                                                           acc[rt], 0, 0, 0);
      }
      const float ce[8] = {cv0.x, cv0.y, cv0.z, cv0.w,
                           cv1.x, cv1.y, cv1.z, cv1.w};
      f32x4 hn4, cn4;
#pragma unroll
      for (int r = 0; r < 4; ++r) {
        const float cn = ce[2 * r] * hsig(acc[1][r]) +
                         ce[2 * r + 1] * hsig(acc[2][r]) +
                         hsig(acc[0][r]) * tanh_fast(acc[4][r]);
        cn4[r] = cn;
        hn4[r] = hsig(acc[3][r]) * tanh_fast(cn);
      }
      if (col == 0) {
        *(f32x4*)(Hb + ((size_t)t << 7) + u0) = hn4;
        *(f32x4*)(Cb + ((size_t)t << 7) + u0) = cn4;
      }
      __syncthreads();
    }
  }
}

extern "C" void kernel_launch(void* const* d_in, const int* in_sizes, int n_in,
                              void* d_out, int out_size, void* d_ws,
                              size_t ws_size, hipStream_t stream) {
  const float* state = (const float*)d_in[0];
  const float* tk    = (const float*)d_in[1];
  const float* Wk    = (const float*)d_in[2];
  const float* Wr    = (const float*)d_in[3];
  const float* bias  = (const float*)d_in[4];
  const int*   child = (const int*)d_in[5];
  const int*   nvp   = (const int*)d_in[6];
  float* H = (float*)d_out;

  // meta (2 MiB): W16 | Wk16 | tkTb | lv | rank | cnt | pos | goff | glist
  char* wsb = (char*)d_ws;
  _Float16* W16   = (_Float16*)(wsb + 0x000000);  // 320K
  _Float16* Wk16  = (_Float16*)(wsb + 0x050000);  // 160K
  short* tkTb     = (short*)(wsb + 0x078000);     // 80K
  unsigned char* lv = (unsigned char*)(wsb + 0x08C000);  // 128K
  short* rank     = (short*)(wsb + 0x0AC000);            // 256K
  int* cnt        = (int*)(wsb + 0x0EC000);
  int* pos        = (int*)(wsb + 0x0F1000);
  int* goff       = (int*)(wsb + 0x0F6000);
  int* glist      = (int*)(wsb + 0x0F7000);              // 512K
  const size_t meta_sz = 2ull * 1024 * 1024;
  const size_t c_bytes = (size_t)M_ * U_ * sizeof(float);  // 64 MiB
  float* C = (float*)(wsb + meta_sz);
  _Float16* XZ = (_Float16*)(wsb + meta_sz + c_bytes);     // 160 MiB

  prep<<<1120, 256, 0, stream>>>(Wr, Wk, tk, W16, Wk16, tkTb);
  x_gemm<<<M_ / 64, 256, 0, stream>>>(state, tkTb, nvp, H, C);
  xz_gemm<<<dim3(M_ / 64, 5), 256, 0, stream>>>(H, Wk16, bias, nvp, XZ);
  levelize<<<B_, 512, 0, stream>>>(child, nvp, lv, rank, cnt);
  offsets<<<1, 64, 0, stream>>>(cnt, pos, goff);
  scatter<<<B_, 256, 0, stream>>>(nvp, lv, rank, pos, glist);
  static const int lg[LPAR] = {0, 512, 512, 256, 256, 128, 128,
                               64, 64, 64, 32, 32, 32, 32};
  for (int l = 1; l < LPAR; ++l)
    level_gemm<<<lg[l], 512, 0, stream>>>(l, W16, child, goff, glist, XZ, H,
                                          C);
  tail_scan<<<B_, 512, 0, stream>>>(W16, child, nvp, pos, cnt, glist, XZ, H,
                                    C);
}